// Round 2
// baseline (180.196 us; speedup 1.0000x reference)
//
#include <hip/hip_runtime.h>

#define S_LEN 2048
#define EMB_D 1024
#define NHEAD 8
#define HDIM 128
#define QK_SCALE 0.08838834764831845f  // 1/sqrt(128)

typedef __bf16 bf16x8 __attribute__((ext_vector_type(8)));
typedef float f32x4 __attribute__((ext_vector_type(4)));

__device__ __forceinline__ unsigned short f2bf(float x) {
    unsigned u = __float_as_uint(x);
    unsigned r = u + 0x7FFFu + ((u >> 16) & 1u);  // RNE
    return (unsigned short)(r >> 16);
}

__device__ __forceinline__ void bfsplit(float x, unsigned short& hi, unsigned short& lo) {
    hi = f2bf(x);
    float hf = __uint_as_float((unsigned)hi << 16);
    lo = f2bf(x - hf);
}

// ---------------- kernel 1: transpose gate weights (3072x8 -> 8x3072, ig rows 0-7, fg rows 8-15)
__global__ __launch_bounds__(256) void ktrans(const float* __restrict__ igk,
                                              const float* __restrict__ fgk,
                                              float* __restrict__ wt) {
    int idx = blockIdx.x * 256 + threadIdx.x;
    if (idx < 3072 * 8) {
        int i = idx >> 3, h = idx & 7;
        wt[h * 3072 + i] = igk[idx];
        wt[(h + 8) * 3072 + i] = fgk[idx];
    }
}

// ---------------- kernel 2: gate preactivations. 4 rows per block.
__global__ __launch_bounds__(256) void kgates(const float* __restrict__ q,
                                              const float* __restrict__ k,
                                              const float* __restrict__ v,
                                              const float* __restrict__ igb,
                                              const float* __restrict__ fgb,
                                              const float* __restrict__ wt,
                                              float* __restrict__ igp,
                                              float* __restrict__ fgp) {
    __shared__ float xs[4][3072];
    const int t = threadIdx.x;
    const int row0 = blockIdx.x * 4;
    #pragma unroll
    for (int p = 0; p < 12; ++p) {
        int c = p * 256 + t;          // float4 index, 0..3071
        int r = c / 768;
        int gcol = (c % 768) * 4;     // 0..3068
        int grow = row0 + r;
        const float* base = (gcol < 1024) ? (q + (size_t)grow * EMB_D + gcol)
                          : (gcol < 2048) ? (k + (size_t)grow * EMB_D + gcol - 1024)
                                          : (v + (size_t)grow * EMB_D + gcol - 2048);
        float4 val = *(const float4*)base;
        *(float4*)&xs[r][gcol] = val;
    }
    __syncthreads();
    const int w = t >> 6, lane = t & 63;
    for (int c = 0; c < 4; ++c) {
        int o = w * 4 + c;  // 0..15
        const float* wc = wt + o * 3072;
        float a0 = 0.f, a1 = 0.f, a2 = 0.f, a3 = 0.f;
        for (int i = lane; i < 3072; i += 64) {
            float wv = wc[i];
            a0 += wv * xs[0][i]; a1 += wv * xs[1][i];
            a2 += wv * xs[2][i]; a3 += wv * xs[3][i];
        }
        #pragma unroll
        for (int m = 32; m; m >>= 1) {
            a0 += __shfl_xor(a0, m); a1 += __shfl_xor(a1, m);
            a2 += __shfl_xor(a2, m); a3 += __shfl_xor(a3, m);
        }
        if (lane == 0) {
            int h = o & 7;
            float bias = (o < 8) ? igb[h] : fgb[h];
            float* dst = (o < 8) ? igp : fgp;
            dst[(size_t)(row0 + 0) * 8 + h] = a0 + bias;
            dst[(size_t)(row0 + 1) * 8 + h] = a1 + bias;
            dst[(size_t)(row0 + 2) * 8 + h] = a2 + bias;
            dst[(size_t)(row0 + 3) * 8 + h] = a3 + bias;
        }
    }
}

// ---------------- kernel 3: per-(b,h) prefix scan: cs = cumsum(logsigmoid(fg)),
// a = ig - cs, pm = prefixmax(a). One block per (b,h), 256 thr x 8 elems.
__global__ __launch_bounds__(256) void kscan(const float* __restrict__ igp,
                                             const float* __restrict__ fgp,
                                             float* __restrict__ a_ws,
                                             float* __restrict__ pm_ws,
                                             float* __restrict__ cs_ws) {
    const int bh = blockIdx.x;
    const int b = bh >> 3, h = bh & 7;
    const int t = threadIdx.x;
    __shared__ float sb[256];
    const size_t base = (size_t)b * S_LEN * 8 + h;
    float lf[8];
    #pragma unroll
    for (int e = 0; e < 8; ++e) {
        float fg = fgp[base + (size_t)(t * 8 + e) * 8];
        lf[e] = fminf(fg, 0.f) - log1pf(__expf(-fabsf(fg)));
    }
    #pragma unroll
    for (int e = 1; e < 8; ++e) lf[e] += lf[e - 1];
    sb[t] = lf[7];
    __syncthreads();
    for (int off = 1; off < 256; off <<= 1) {
        float vv = sb[t];
        float other = (t >= off) ? sb[t - off] : 0.f;
        __syncthreads();
        sb[t] = vv + other;
        __syncthreads();
    }
    float basex = sb[t] - lf[7];  // exclusive prefix over threads
    float cs[8], ai[8];
    const int obase = bh * S_LEN + t * 8;
    #pragma unroll
    for (int e = 0; e < 8; ++e) {
        cs[e] = basex + lf[e];
        cs_ws[obase + e] = cs[e];
        ai[e] = igp[base + (size_t)(t * 8 + e) * 8] - cs[e];
        a_ws[obase + e] = ai[e];
    }
    float am[8];
    am[0] = ai[0];
    #pragma unroll
    for (int e = 1; e < 8; ++e) am[e] = fmaxf(am[e - 1], ai[e]);
    __syncthreads();
    sb[t] = am[7];
    __syncthreads();
    for (int off = 1; off < 256; off <<= 1) {
        float vv = sb[t];
        float other = (t >= off) ? sb[t - off] : -INFINITY;
        __syncthreads();
        sb[t] = fmaxf(vv, other);
        __syncthreads();
    }
    float exm = (t == 0) ? -INFINITY : sb[t - 1];
    #pragma unroll
    for (int e = 0; e < 8; ++e) pm_ws[obase + e] = fmaxf(exm, am[e]);
}

// ---------------- kernel 4: main causal decay-attention core + RMSNorm.
// 256 blocks, 512 threads (8 waves). Block = (b,h) x row-tile-pair {r, 31-r}, BM=BN=64.
// QK^T is computed in split precision: q,k staged as bf16 hi+lo planes,
// qk = qh*kh + ql*kh + qh*kl (3 MFMAs) -> additive score error ~1e-5 (the
// amplifying error path). C and V stay single bf16 (signal-proportional errors).
__global__ __launch_bounds__(512) void kmain(const float* __restrict__ q,
                                             const float* __restrict__ k,
                                             const float* __restrict__ v,
                                             const float* __restrict__ a_ws,
                                             const float* __restrict__ pm_ws,
                                             const float* __restrict__ cs_ws,
                                             float* __restrict__ out) {
    __shared__ __align__(16) unsigned short Qs[2][64 * 128];  // [hi/lo], row stride 256B, swz (r&7)<<4
    __shared__ __align__(16) unsigned short Ks[2][64 * 128];
    __shared__ __align__(16) unsigned short Vt[128 * 64];  // transposed V [d][j], swz ((d&7)^((d>>3)&7))<<4
    __shared__ __align__(16) unsigned short Cs[64 * 64];   // bf16 C, row stride 128B, swz (i&7)<<4
    __shared__ float a_sh[64];
    __shared__ float red[2][64];

    const int idx = blockIdx.x;
    const int xcd = idx & 7;           // keep all tiles of one bh on one XCD (L2 locality)
    const int rest = idx >> 3;
    const int pair = rest & 15;
    const int bh = ((rest >> 4) << 3) | xcd;
    const int b = bh >> 3, h = bh & 7;
    const int t = threadIdx.x;
    const int w = t >> 6, lane = t & 63;
    const int wrow = w & 3, whalf = w >> 2;
    const int lg = lane >> 4, ll = lane & 15;

    const float* qb = q + ((size_t)b * S_LEN) * EMB_D + h * HDIM;
    const float* kb = k + ((size_t)b * S_LEN) * EMB_D + h * HDIM;
    const float* vb = v + ((size_t)b * S_LEN) * EMB_D + h * HDIM;
    const float* aw = a_ws + bh * S_LEN;
    const float* pw = pm_ws + bh * S_LEN;
    const float* cw = cs_ws + bh * S_LEN;
    float* ob = out + ((size_t)b * S_LEN) * EMB_D + h * HDIM;

    for (int rti = 0; rti < 2; ++rti) {
        const int rt = rti ? (31 - pair) : pair;
        const int row0 = rt * 64;
        __syncthreads();
        // stage Q tile (pre-scaled by 1/sqrt(128)) as hi+lo planes
        #pragma unroll
        for (int p = 0; p < 4; ++p) {
            int c = p * 512 + t;
            int r = c >> 5, c4 = c & 31;
            float4 f = *(const float4*)(qb + (size_t)(row0 + r) * EMB_D + c4 * 4);
            ushort4 hh, ql_;
            bfsplit(f.x * QK_SCALE, hh.x, ql_.x);
            bfsplit(f.y * QK_SCALE, hh.y, ql_.y);
            bfsplit(f.z * QK_SCALE, hh.z, ql_.z);
            bfsplit(f.w * QK_SCALE, hh.w, ql_.w);
            int off = (r * 256 + c4 * 8) ^ ((r & 7) << 4);
            *(ushort4*)((char*)Qs[0] + off) = hh;
            *(ushort4*)((char*)Qs[1] + off) = ql_;
        }
        float pmv[4], csv[4];
        #pragma unroll
        for (int reg = 0; reg < 4; ++reg) {
            int i = row0 + 16 * wrow + 4 * lg + reg;
            pmv[reg] = pw[i];
            csv[reg] = cw[i];
        }
        __syncthreads();
        // hoist Q fragments (hi+lo) to registers (invariant over col tiles)
        bf16x8 qfh[4], qfl[4];
        #pragma unroll
        for (int kk = 0; kk < 4; ++kk) {
            int rowA = 16 * wrow + ll;
            int off = (rowA * 256 + lg * 16 + kk * 64) ^ ((rowA & 7) << 4);
            qfh[kk] = *(const bf16x8*)((const char*)Qs[0] + off);
            qfl[kk] = *(const bf16x8*)((const char*)Qs[1] + off);
        }
        f32x4 zero4 = {0.f, 0.f, 0.f, 0.f};
        f32x4 accO[4];
        #pragma unroll
        for (int i2 = 0; i2 < 4; ++i2) accO[i2] = zero4;
        float rs[4] = {0.f, 0.f, 0.f, 0.f};

        for (int ct = 0; ct <= rt; ++ct) {
            const int col0 = ct * 64;
            // stage K tile (hi+lo) + transposed V tile
            #pragma unroll
            for (int p = 0; p < 4; ++p) {
                int c = p * 512 + t;
                int r = c >> 5, c4 = c & 31;
                float4 f = *(const float4*)(kb + (size_t)(col0 + r) * EMB_D + c4 * 4);
                ushort4 hh, kl_;
                bfsplit(f.x, hh.x, kl_.x);
                bfsplit(f.y, hh.y, kl_.y);
                bfsplit(f.z, hh.z, kl_.z);
                bfsplit(f.w, hh.w, kl_.w);
                int off = (r * 256 + c4 * 8) ^ ((r & 7) << 4);
                *(ushort4*)((char*)Ks[0] + off) = hh;
                *(ushort4*)((char*)Ks[1] + off) = kl_;
                float4 g = *(const float4*)(vb + (size_t)(col0 + r) * EMB_D + c4 * 4);
                int d0 = c4 * 4;
                #pragma unroll
                for (int e = 0; e < 4; ++e) {
                    int d = d0 + e;
                    float val = (e == 0) ? g.x : (e == 1) ? g.y : (e == 2) ? g.z : g.w;
                    int swz = ((d & 7) ^ ((d >> 3) & 7)) << 4;
                    *(unsigned short*)((char*)Vt + ((d * 128 + r * 2) ^ swz)) = f2bf(val);
                }
            }
            if (t < 64) a_sh[t] = aw[col0 + t];
            __syncthreads();

            // QK^T for this wave's 16x32 output slice (3-term split precision)
            f32x4 accS[2];
            accS[0] = zero4; accS[1] = zero4;
            #pragma unroll
            for (int kk = 0; kk < 4; ++kk) {
                #pragma unroll
                for (int cc = 0; cc < 2; ++cc) {
                    int cf = 2 * whalf + cc;
                    int rowB = 16 * cf + ll;
                    int off = (rowB * 256 + lg * 16 + kk * 64) ^ ((rowB & 7) << 4);
                    bf16x8 kh = *(const bf16x8*)((const char*)Ks[0] + off);
                    bf16x8 klo = *(const bf16x8*)((const char*)Ks[1] + off);
                    accS[cc] = __builtin_amdgcn_mfma_f32_16x16x32_bf16(qfh[kk], kh, accS[cc], 0, 0, 0);
                    accS[cc] = __builtin_amdgcn_mfma_f32_16x16x32_bf16(qfl[kk], kh, accS[cc], 0, 0, 0);
                    accS[cc] = __builtin_amdgcn_mfma_f32_16x16x32_bf16(qfh[kk], klo, accS[cc], 0, 0, 0);
                }
            }
            // decay * mask, rowsum, store C (bf16) to LDS
            const bool diag = (ct == rt);
            #pragma unroll
            for (int cc = 0; cc < 2; ++cc) {
                int cf = 2 * whalf + cc;
                int jl = 16 * cf + ll;
                int jg = col0 + jl;
                float aj = a_sh[jl];
                #pragma unroll
                for (int reg = 0; reg < 4; ++reg) {
                    int il = 16 * wrow + 4 * lg + reg;
                    float cval = accS[cc][reg] * __expf(aj - pmv[reg]);
                    if (diag && jg > row0 + il) cval = 0.f;
                    rs[reg] += cval;
                    *(unsigned short*)((char*)Cs + ((il * 128 + jl * 2) ^ ((il & 7) << 4))) = f2bf(cval);
                }
            }
            __syncthreads();
            // PV: out += C(64x64) * V(64x128), this wave's 16-row strip x 64-col half
            #pragma unroll
            for (int kk = 0; kk < 2; ++kk) {
                int rowA = 16 * wrow + ll;
                int offA = (rowA * 128 + lg * 16 + kk * 64) ^ ((rowA & 7) << 4);
                bf16x8 afr = *(const bf16x8*)((const char*)Cs + offA);
                #pragma unroll
                for (int cc = 0; cc < 4; ++cc) {
                    int vf = 4 * whalf + cc;
                    int rowB = 16 * vf + ll;  // = d
                    int swz = ((rowB & 7) ^ ((rowB >> 3) & 7)) << 4;
                    int offB = (rowB * 128 + ((lg * 16 + kk * 64) ^ swz));
                    bf16x8 bfr = *(const bf16x8*)((const char*)Vt + offB);
                    accO[cc] = __builtin_amdgcn_mfma_f32_16x16x32_bf16(afr, bfr, accO[cc], 0, 0, 0);
                }
            }
            __syncthreads();
        }  // ct

        // ---- finalize: rowsum reduce, normalizer, RMSNorm, store
        #pragma unroll
        for (int m2 = 1; m2 < 16; m2 <<= 1) {
            #pragma unroll
            for (int reg = 0; reg < 4; ++reg) rs[reg] += __shfl_xor(rs[reg], m2);
        }
        if (ll == 0) {
            int basei = 16 * wrow + 4 * lg;
            red[whalf][basei + 0] = rs[0]; red[whalf][basei + 1] = rs[1];
            red[whalf][basei + 2] = rs[2]; red[whalf][basei + 3] = rs[3];
        }
        __syncthreads();
        float norm[4];
        #pragma unroll
        for (int reg = 0; reg < 4; ++reg) {
            int il = 16 * wrow + 4 * lg + reg;
            float rstot = red[0][il] + red[1][il];
            norm[reg] = fmaxf(fabsf(rstot), __expf(-(csv[reg] + pmv[reg]))) + 1e-6f;
        }
        float ss[4] = {0.f, 0.f, 0.f, 0.f};
        #pragma unroll
        for (int cc = 0; cc < 4; ++cc) {
            #pragma unroll
            for (int reg = 0; reg < 4; ++reg) {
                float hv = accO[cc][reg] / norm[reg];
                ss[reg] += hv * hv;
            }
        }
        #pragma unroll
        for (int m2 = 1; m2 < 16; m2 <<= 1) {
            #pragma unroll
            for (int reg = 0; reg < 4; ++reg) ss[reg] += __shfl_xor(ss[reg], m2);
        }
        __syncthreads();
        if (ll == 0) {
            int basei = 16 * wrow + 4 * lg;
            red[whalf][basei + 0] = ss[0]; red[whalf][basei + 1] = ss[1];
            red[whalf][basei + 2] = ss[2]; red[whalf][basei + 3] = ss[3];
        }
        __syncthreads();
        #pragma unroll
        for (int reg = 0; reg < 4; ++reg) {
            int il = 16 * wrow + 4 * lg + reg;
            float sst = red[0][il] + red[1][il];
            float scl = rsqrtf(sst * (1.0f / 128.0f) + 1e-6f) / norm[reg];
            int ig_ = row0 + il;
            #pragma unroll
            for (int cc = 0; cc < 4; ++cc) {
                int d = 16 * (4 * whalf + cc) + ll;
                ob[(size_t)ig_ * EMB_D + d] = accO[cc][reg] * scl;
            }
        }
    }  // rti
}

extern "C" void kernel_launch(void* const* d_in, const int* in_sizes, int n_in,
                              void* d_out, int out_size, void* d_ws, size_t ws_size,
                              hipStream_t stream) {
    const float* q   = (const float*)d_in[0];
    const float* k   = (const float*)d_in[1];
    const float* v   = (const float*)d_in[2];
    const float* igk = (const float*)d_in[3];
    const float* igb = (const float*)d_in[4];
    const float* fgk = (const float*)d_in[5];
    const float* fgb = (const float*)d_in[6];
    float* out = (float*)d_out;
    float* ws  = (float*)d_ws;

    float* wt   = ws;            // 16*3072        = 49152 floats
    float* igp  = ws + 49152;    // 4096*8         = 32768
    float* fgp  = ws + 81920;    // 32768
    float* a_w  = ws + 114688;   // 16*2048        = 32768
    float* pm_w = ws + 147456;   // 32768
    float* cs_w = ws + 180224;   // 32768  (total ~852 KB)

    ktrans<<<96, 256, 0, stream>>>(igk, fgk, wt);
    kgates<<<1024, 256, 0, stream>>>(q, k, v, igb, fgb, wt, igp, fgp);
    kscan<<<16, 256, 0, stream>>>(igp, fgp, a_w, pm_w, cs_w);
    kmain<<<256, 512, 0, stream>>>(q, k, v, a_w, pm_w, cs_w, out);
}